// Round 6
// baseline (2547.281 us; speedup 1.0000x reference)
//
#include <hip/hip_runtime.h>

// GraphLSTM-VAE on MI355X — round 6: enc/dec split (phase evidence) +
// register-prefetched weight fragments (issued across barriers) +
// h-interleaved coalesced pnl weight layout.
// Cells keep round-5 structure: Y=xh@W (MFMA, prepacked B-frags) -> in-wave
// A-mix via per-wave LDS scratch -> gates; ping-pong h banks, node-major XN.

typedef unsigned short u16;
typedef unsigned int u32;
typedef short bf16x8 __attribute__((ext_vector_type(8)));
typedef float f32x4 __attribute__((ext_vector_type(4)));

// ---- output layout (fp32 elements) ----
#define O_OUT 0
#define O_Z   4194304
#define O_MU  4456448
#define O_LV  4718592
#define O_OLV 4980736

// ---- workspace layout (u16 elements) ----
#define WS_ABF  0          // Ahat bf16 [32][40]
#define WS_PEN0 1280
#define WS_PEN1 83200
#define WS_PDE0 214272
#define WS_PDE1 296192
#define WS_PHO  427264     // WhoP  [h/8][n*32+d][8] bf16 (131072)
#define WS_PLV  558336     // WholvP[h/8][n*32+d][8] bf16 (131072)
#define WS_ST   689408     // per-block state: 64 x 32768 u16
#define WS_H1   2786560    // dec h1 save: [b*63+s][n*128+h] bf16 (16515072)
#define WS_NEED_BYTES 38603264ull
// state sublayout (u16 offsets within 32768): H0 0 | H1 4096 | X 8192 |
//   C0 fp32 @10240 (8192 u16) | C1 fp32 @18432 (8192 u16)

#define XSTR 552   // XN row stride (u16): x 0..31 | h0A 32 | h0B 160 | h1A 288 | h1B 416

__device__ __forceinline__ u16 f2b(float f){
  unsigned x = __float_as_uint(f);
  x += 0x7fffu + ((x>>16)&1u);           // RNE
  return (u16)(x>>16);
}
__device__ __forceinline__ float b2f(u16 u){ return __uint_as_float(((unsigned)u)<<16); }
__device__ __forceinline__ float blo(unsigned u){ return __uint_as_float(u<<16); }
__device__ __forceinline__ float bhi(unsigned u){ return __uint_as_float(u & 0xffff0000u); }
__device__ __forceinline__ float sigm(float x){ return 1.f/(1.f+__expf(-x)); }
__device__ __forceinline__ float tanh_(float x){
  float e = __expf(-2.f*fabsf(x));
  float r = (1.f-e)/(1.f+e);
  return __builtin_copysignf(r, x);
}

// ============ prepack: GCN-normalized adjacency -> bf16 [32][40] ============
__global__ void adj_kernel(const int* __restrict__ ei, u16* __restrict__ ws)
{
  __shared__ float As[1024];
  __shared__ float dinv[32];
  const int tid = threadIdx.x;
  for (int e = tid; e < 1024; e += 256) As[e] = 0.f;
  __syncthreads();
  atomicAdd(&As[ei[256 + tid]*32 + ei[tid]], 1.f);   // A[dst][src] += 1 (E=256)
  __syncthreads();
  if (tid < 32) As[tid*33] += 1.f;                    // +I
  __syncthreads();
  if (tid < 32){
    float s = 0.f;
    for (int j=0;j<32;++j) s += As[tid*32 + j];
    dinv[tid] = rsqrtf(s);
  }
  __syncthreads();
  for (int e = tid; e < 1280; e += 256){
    int i = e / 40, j = e % 40;
    float v = (j < 32) ? As[i*32 + j]*dinv[i]*dinv[j] : 0.f;
    ws[WS_ABF + e] = f2b(v);
  }
}

// ============ prepack: fp32 weights -> bf16 MFMA-B frags + interleaved pnl ============
__global__ void pack_kernel(const float* __restrict__ Wen0, const float* __restrict__ Wen1,
                            const float* __restrict__ Wde0, const float* __restrict__ Wde1,
                            const float* __restrict__ Who,  const float* __restrict__ Wholv,
                            u16* __restrict__ ws)
{
  int id = blockIdx.x*256 + threadIdx.x;      // 336*256 = 86016 exactly
  if (id < 53248){
    const float* W; int KS, dstoff, lid;
    if (id < 10240){ W = Wen0; KS = 5; dstoff = WS_PEN0; lid = id; }
    else if (id < 26624){ W = Wen1; KS = 8; dstoff = WS_PEN1; lid = id - 10240; }
    else if (id < 36864){ W = Wde0; KS = 5; dstoff = WS_PDE0; lid = id - 26624; }
    else { W = Wde1; KS = 8; dstoff = WS_PDE1; lid = id - 36864; }
    int l = lid & 63, rest = lid >> 6;
    int ks = rest % KS, nt = rest / KS;
    int n  = nt*16 + (l & 15);
    int k0 = ks*32 + (l >> 4)*8;
    u16 tmp[8];
    #pragma unroll
    for (int j=0;j<8;++j) tmp[j] = f2b(W[(k0 + j)*512 + n]);
    uint4 v;
    v.x = (unsigned)tmp[0] | ((unsigned)tmp[1] << 16);
    v.y = (unsigned)tmp[2] | ((unsigned)tmp[3] << 16);
    v.z = (unsigned)tmp[4] | ((unsigned)tmp[5] << 16);
    v.w = (unsigned)tmp[6] | ((unsigned)tmp[7] << 16);
    *(uint4*)&ws[dstoff + lid*8] = v;
  } else {
    // WP[hb][n*32+d][8] <- W[(n*128 + hb*8+j)*32 + d]
    int e = id - 53248;                        // [0, 32768)
    const float* src = (e < 16384) ? Who : Wholv;
    int dsto = (e < 16384) ? WS_PHO : WS_PLV;
    e &= 16383;
    int n = e >> 9, r = e & 511;
    int d = r >> 4, hb = r & 15;
    u16 tmp[8];
    #pragma unroll
    for (int j=0;j<8;++j) tmp[j] = f2b(src[(n*128 + hb*8 + j)*32 + d]);
    uint4 v;
    v.x = (unsigned)tmp[0] | ((unsigned)tmp[1] << 16);
    v.y = (unsigned)tmp[2] | ((unsigned)tmp[3] << 16);
    v.z = (unsigned)tmp[4] | ((unsigned)tmp[5] << 16);
    v.w = (unsigned)tmp[6] | ((unsigned)tmp[7] << 16);
    *(uint4*)&ws[dsto + (hb*8192 + (n*32 + d)*8)] = v;
  }
}

// ============ cell helpers ============
template<int KS>
__device__ __forceinline__ void prefetch_w(const u16* __restrict__ PW,
                                           int lane, int wave, bf16x8* dst)
{
  const bf16x8* PW8 = (const bf16x8*)PW;
  #pragma unroll
  for (int ks=0; ks<KS; ++ks)
    #pragma unroll
    for (int g=0; g<4; ++g)
      dst[ks*4+g] = PW8[((g*8 + wave)*KS + ks)*64 + lane];
}

template<int KS, int N0>
__device__ __forceinline__ void cell_z(
    const bf16x8* bw, const float* bias4,
    const u16* XN, const u16* Abf, u16* yt,
    int kb0, int kb1, int l15, int lq,
    f32x4 (&acc2)[2][4])
{
  f32x4 acc[2][4];
  #pragma unroll
  for (int mt=0;mt<2;++mt)
    #pragma unroll
    for (int g=0;g<4;++g){ f32x4 z = {0.f,0.f,0.f,0.f}; acc[mt][g] = z; }
  #pragma unroll
  for (int ks=0; ks<KS; ++ks){
    const int off = (ks < N0) ? (kb0 + ks*32) : (kb1 + (ks - N0)*32);
    bf16x8 a0 = *(const bf16x8*)&XN[l15*XSTR + off + lq*8];
    bf16x8 a1 = *(const bf16x8*)&XN[(16 + l15)*XSTR + off + lq*8];
    #pragma unroll
    for (int g=0; g<4; ++g){
      acc[0][g] = __builtin_amdgcn_mfma_f32_16x16x32_bf16(a0, bw[ks*4+g], acc[0][g], 0, 0, 0);
      acc[1][g] = __builtin_amdgcn_mfma_f32_16x16x32_bf16(a1, bw[ks*4+g], acc[1][g], 0, 0, 0);
    }
  }
  // in-wave A-mix: acc2 = Ahat @ Y + b, through per-wave yt scratch (lgkm only)
  u32* yt32 = (u32*)yt;
  bf16x8 afr0 = *(const bf16x8*)&Abf[l15*40 + lq*8];
  bf16x8 afr1 = *(const bf16x8*)&Abf[(16 + l15)*40 + lq*8];
  #pragma unroll
  for (int hh=0; hh<2; ++hh){
    #pragma unroll
    for (int g2=0; g2<2; ++g2){
      const int g = hh*2 + g2;
      #pragma unroll
      for (int mt=0; mt<2; ++mt){
        u32 lo = (u32)f2b(acc[mt][g][0]) | ((u32)f2b(acc[mt][g][1]) << 16);
        u32 hi = (u32)f2b(acc[mt][g][2]) | ((u32)f2b(acc[mt][g][3]) << 16);
        const int base = (g2*16 + l15)*20 + mt*8 + lq*2;
        yt32[base]     = lo;
        yt32[base + 1] = hi;
      }
    }
    #pragma unroll
    for (int g2=0; g2<2; ++g2){
      const int g = hh*2 + g2;
      bf16x8 bfr = *(const bf16x8*)&yt[(g2*16 + l15)*40 + lq*8];
      f32x4 vb = {bias4[g], bias4[g], bias4[g], bias4[g]};
      acc2[0][g] = __builtin_amdgcn_mfma_f32_16x16x32_bf16(afr0, bfr, vb, 0, 0, 0);
      acc2[1][g] = __builtin_amdgcn_mfma_f32_16x16x32_bf16(afr1, bfr, vb, 0, 0, 0);
    }
  }
}

__device__ __forceinline__ void gates(
    f32x4 (&acc2)[2][4], f32x4 (&cst)[2],
    u16* XN, int hwrite, int col, int lq)
{
  #pragma unroll
  for (int mt=0;mt<2;++mt){
    #pragma unroll
    for (int q=0;q<4;++q){
      float iv = sigm(acc2[mt][0][q]);
      float fv = sigm(acc2[mt][1][q]);
      float gv = tanh_(acc2[mt][2][q]);
      float ov = sigm(acc2[mt][3][q]);
      float c  = fv*cst[mt][q] + iv*gv;
      cst[mt][q] = c;
      XN[(mt*16 + lq*4 + q)*XSTR + hwrite + col] = f2b(ov*tanh_(c));
    }
  }
}

// ============ encoder kernel: 64 steps + mu/z + out_last + state save ============
__global__ __launch_bounds__(512, 2) void enc_main(
  const float* __restrict__ ts,
  const float* __restrict__ ben0, const float* __restrict__ ben1,
  const float* __restrict__ Wmu, const float* __restrict__ bmu,
  const float* __restrict__ Wlv, const float* __restrict__ blv,
  const float* __restrict__ bho, const float* __restrict__ bholv,
  const float* __restrict__ Wholv,
  const float* __restrict__ eps,
  const u16* __restrict__ ws, u16* __restrict__ wsST,
  float* __restrict__ dout)
{
  __shared__ __align__(16) u16 XN[32*XSTR];
  __shared__ __align__(16) u16 Abf[32*40];
  __shared__ __align__(16) u16 Ytr[8*32*40];
  float* zl = (float*)Ytr;

  const int tid  = threadIdx.x;
  const int lane = tid & 63, wave = tid >> 6;
  const int l15  = lane & 15, lq = lane >> 4;
  const int b    = blockIdx.x;
  const int col  = wave*16 + l15;
  u16* yt = Ytr + wave*(32*40);

  for (int e = tid; e < 1280;    e += 512) Abf[e] = ws[WS_ABF + e];
  for (int e = tid; e < 32*XSTR; e += 512) XN[e] = 0;
  f32x4 c0[2], c1[2];
  { f32x4 zz = {0.f,0.f,0.f,0.f}; c0[0]=c0[1]=c1[0]=c1[1]=zz; }
  float biE0[4], biE1[4];
  #pragma unroll
  for (int g=0; g<4; ++g){ biE0[g] = ben0[g*128+col]; biE1[g] = ben1[g*128+col]; }
  bf16x8 w0[20], w1[32];
  prefetch_w<5>(ws+WS_PEN0, lane, wave, w0);     // in flight across first barrier
  __syncthreads();
  {
    const float* xp = ts + (size_t)(b*64)*1024;
    for (int e = tid; e < 1024; e += 512)
      XN[(e >> 5)*XSTR + (e & 31)] = f2b(xp[e]);
  }
  __syncthreads();

  for (int t=0; t<64; ++t){
    const int ph = t & 1;
    f32x4 z0[2][4], z1[2][4];
    cell_z<5,1>(w0, biE0, XN, Abf, yt, 0, 32 + 128*ph, l15, lq, z0);
    prefetch_w<8>(ws+WS_PEN1, lane, wave, w1);   // overlap gates + barrier
    gates(z0, c0, XN, 32 + 128*(1-ph), col, lq);
    __syncthreads();
    if (t < 63){
      const float* xp = ts + (size_t)(b*64 + t + 1)*1024;
      for (int e = tid; e < 1024; e += 512)
        XN[(e >> 5)*XSTR + (e & 31)] = f2b(xp[e]);
    }
    cell_z<8,4>(w1, biE1, XN, Abf, yt, 32 + 128*(1-ph), 288 + 128*ph, l15, lq, z1);
    if (t < 63) prefetch_w<5>(ws+WS_PEN0, lane, wave, w0);  // overlap gates + barrier
    gates(z1, c1, XN, 288 + 128*(1-ph), col, lq);
    __syncthreads();
  }
  // final: h0 @ 32, h1 @ 288

  // ---- mu / logvar / zlat ----
  for (int k=0;k<8;++k){
    int idx = tid + k*512;
    int n = idx >> 7, o = idx & 127;
    float am = bmu[idx];
    float al = blv[idx];
    #pragma unroll 4
    for (int h=0; h<128; ++h){
      float hv = b2f(XN[n*XSTR + 288 + h]);
      am += hv * Wmu[(n*128 + h)*128 + o];
      al += hv * Wlv[(n*128 + h)*128 + o];
    }
    float zv = am + eps[b*4096 + idx] * __expf(al);
    zl[idx] = zv;
    dout[O_MU + b*4096 + idx] = am;
    dout[O_LV + b*4096 + idx] = al;
    dout[O_Z  + b*4096 + idx] = zv;
  }
  __syncthreads();
  // ---- out_last / outlv_last ----
  const u16* whoP = ws + WS_PHO;
  #pragma unroll
  for (int k=0;k<2;++k){
    int idx = tid + k*512;
    int n = idx >> 5, d = idx & 31;
    float a  = bho[idx];
    float a2 = bholv[idx];
    #pragma unroll 4
    for (int hb=0; hb<16; ++hb){
      uint4 wv = *(const uint4*)&whoP[hb*8192 + idx*8];
      const float* zp = &zl[n*128 + hb*8];
      a += zp[0]*blo(wv.x) + zp[1]*bhi(wv.x) + zp[2]*blo(wv.y) + zp[3]*bhi(wv.y)
         + zp[4]*blo(wv.z) + zp[5]*bhi(wv.z) + zp[6]*blo(wv.w) + zp[7]*bhi(wv.w);
    }
    for (int h=0; h<128; ++h)
      a2 += zl[n*128 + h] * Wholv[(n*128+h)*32 + d];
    dout[O_OUT + (size_t)(b*64 + 63)*1024 + idx] = a;
    dout[O_OLV + (size_t)(b*64 + 63)*1024 + idx] = a2;
    XN[n*XSTR + d] = f2b(a);                    // feedback x
  }
  __syncthreads();
  // ---- save state for decoder ----
  u16* st = wsST + (size_t)b*32768;
  for (int e = tid; e < 4096; e += 512){
    st[e]        = XN[(e >> 7)*XSTR + 32  + (e & 127)];   // h0
    st[4096 + e] = XN[(e >> 7)*XSTR + 288 + (e & 127)];   // h1
  }
  for (int e = tid; e < 1024; e += 512)
    st[8192 + e] = XN[(e >> 5)*XSTR + (e & 31)];          // x (out_last)
  float* cs0 = (float*)(st + 10240);
  float* cs1 = (float*)(st + 18432);
  #pragma unroll
  for (int mt=0;mt<2;++mt)
    #pragma unroll
    for (int q=0;q<4;++q){
      int node = mt*16 + lq*4 + q;
      cs0[node*128 + col] = c0[mt][q];
      cs1[node*128 + col] = c1[mt][q];
    }
}

// ============ decoder kernel: 63 steps ============
template<bool SAVE>
__global__ __launch_bounds__(512, 2) void dec_main(
  const float* __restrict__ bde0, const float* __restrict__ bde1,
  const float* __restrict__ bho, const float* __restrict__ bholv,
  const u16* __restrict__ ws, const u16* __restrict__ wsST, u16* __restrict__ wsH1,
  float* __restrict__ dout)
{
  __shared__ __align__(16) u16 XN[32*XSTR];
  __shared__ __align__(16) u16 Abf[32*40];
  __shared__ __align__(16) u16 Ytr[8*32*40];

  const int tid  = threadIdx.x;
  const int lane = tid & 63, wave = tid >> 6;
  const int l15  = lane & 15, lq = lane >> 4;
  const int b    = blockIdx.x;
  const int col  = wave*16 + l15;
  u16* yt = Ytr + wave*(32*40);

  for (int e = tid; e < 1280; e += 512) Abf[e] = ws[WS_ABF + e];
  const u16* st = wsST + (size_t)b*32768;
  for (int e = tid; e < 4096; e += 512){
    XN[(e >> 7)*XSTR + 32  + (e & 127)] = st[e];          // h0 -> bank A
    XN[(e >> 7)*XSTR + 288 + (e & 127)] = st[4096 + e];   // h1 -> bank A
  }
  for (int e = tid; e < 1024; e += 512)
    XN[(e >> 5)*XSTR + (e & 31)] = st[8192 + e];          // x
  f32x4 c0[2], c1[2];
  {
    const float* cs0 = (const float*)(st + 10240);
    const float* cs1 = (const float*)(st + 18432);
    #pragma unroll
    for (int mt=0;mt<2;++mt)
      #pragma unroll
      for (int q=0;q<4;++q){
        int node = mt*16 + lq*4 + q;
        c0[mt][q] = cs0[node*128 + col];
        c1[mt][q] = cs1[node*128 + col];
      }
  }
  float biD0[4], biD1[4];
  #pragma unroll
  for (int g=0; g<4; ++g){ biD0[g] = bde0[g*128+col]; biD1[g] = bde1[g*128+col]; }
  const u16* whoP = ws + WS_PHO;
  const u16* wlvP = ws + WS_PLV;
  bf16x8 w0[20], w1[32];
  prefetch_w<5>(ws+WS_PDE0, lane, wave, w0);
  __syncthreads();

  for (int s=0; s<63; ++s){
    const int pg = s & 1;
    f32x4 z0[2][4], z1[2][4];
    cell_z<5,1>(w0, biD0, XN, Abf, yt, 0, 32 + 128*pg, l15, lq, z0);
    prefetch_w<8>(ws+WS_PDE1, lane, wave, w1);
    gates(z0, c0, XN, 32 + 128*(1-pg), col, lq);
    __syncthreads();
    cell_z<8,4>(w1, biD1, XN, Abf, yt, 32 + 128*(1-pg), 288 + 128*pg, l15, lq, z1);
    if (s < 62) prefetch_w<5>(ws+WS_PDE0, lane, wave, w0);
    gates(z1, c1, XN, 288 + 128*(1-pg), col, lq);
    __syncthreads();
    const int h1b = 288 + 128*(1-pg);
    if (SAVE){
      u16* dst = wsH1 + (size_t)(b*63 + s)*4096;
      for (int k=0;k<8;++k){
        int idx = tid + k*512;
        dst[idx] = XN[(idx >> 7)*XSTR + h1b + (idx & 127)];
      }
    }
    const int tt = 62 - s;
    #pragma unroll
    for (int k=0;k<2;++k){
      int idx = tid + k*512;
      int n = idx >> 5, d = idx & 31;
      float a = bho[idx];
      if (SAVE){
        #pragma unroll 4
        for (int hb=0; hb<16; ++hb){
          uint4 hv = *(const uint4*)&XN[n*XSTR + h1b + hb*8];
          uint4 wv = *(const uint4*)&whoP[hb*8192 + idx*8];
          a += blo(hv.x)*blo(wv.x) + bhi(hv.x)*bhi(wv.x);
          a += blo(hv.y)*blo(wv.y) + bhi(hv.y)*bhi(wv.y);
          a += blo(hv.z)*blo(wv.z) + bhi(hv.z)*bhi(wv.z);
          a += blo(hv.w)*blo(wv.w) + bhi(hv.w)*bhi(wv.w);
        }
      } else {
        float a2 = bholv[idx];
        #pragma unroll 4
        for (int hb=0; hb<16; ++hb){
          uint4 hv = *(const uint4*)&XN[n*XSTR + h1b + hb*8];
          uint4 wv = *(const uint4*)&whoP[hb*8192 + idx*8];
          uint4 w2 = *(const uint4*)&wlvP[hb*8192 + idx*8];
          float s0=blo(hv.x), s1=bhi(hv.x), s2=blo(hv.y), s3=bhi(hv.y);
          float s4=blo(hv.z), s5=bhi(hv.z), s6=blo(hv.w), s7=bhi(hv.w);
          a  += s0*blo(wv.x) + s1*bhi(wv.x) + s2*blo(wv.y) + s3*bhi(wv.y)
              + s4*blo(wv.z) + s5*bhi(wv.z) + s6*blo(wv.w) + s7*bhi(wv.w);
          a2 += s0*blo(w2.x) + s1*bhi(w2.x) + s2*blo(w2.y) + s3*bhi(w2.y)
              + s4*blo(w2.z) + s5*bhi(w2.z) + s6*blo(w2.w) + s7*bhi(w2.w);
        }
        dout[O_OLV + (size_t)(b*64 + tt)*1024 + idx] = a2;
      }
      dout[O_OUT + (size_t)(b*64 + tt)*1024 + idx] = a;
      XN[n*XSTR + d] = f2b(a);                  // feedback x
    }
    __syncthreads();
  }
}

// ============ epilogue: output_logvar for t<63 (SAVE path) ============
__global__ __launch_bounds__(256) void outlv_kernel(
    const u16* __restrict__ wsH1, const u16* __restrict__ ws,
    const float* __restrict__ bholv, float* __restrict__ dout)
{
  const int n = blockIdx.x, t = blockIdx.y, tid = threadIdx.x;  // t in [0,63)
  __shared__ __align__(16) u16 Ls[64*128];
  const int s = 62 - t;
  for (int e = tid; e < 8192; e += 256){
    int b = e >> 7;
    Ls[e] = wsH1[(size_t)(b*63 + s)*4096 + n*128 + (e & 127)];
  }
  __syncthreads();
  const int d = tid & 31, bq = tid >> 5;
  const float bias = bholv[n*32 + d];
  for (int b = bq; b < 64; b += 8){
    float acc = bias;
    #pragma unroll 4
    for (int hb = 0; hb < 16; ++hb){
      uint4 sv = *(const uint4*)&Ls[b*128 + hb*8];
      uint4 wv = *(const uint4*)&ws[WS_PLV + hb*8192 + (n*32 + d)*8];
      acc += blo(sv.x)*blo(wv.x) + bhi(sv.x)*bhi(wv.x);
      acc += blo(sv.y)*blo(wv.y) + bhi(sv.y)*bhi(wv.y);
      acc += blo(sv.z)*blo(wv.z) + bhi(sv.z)*bhi(wv.z);
      acc += blo(sv.w)*blo(wv.w) + bhi(sv.w)*bhi(wv.w);
    }
    dout[O_OLV + (size_t)(b*64 + t)*1024 + n*32 + d] = acc;
  }
}

extern "C" void kernel_launch(void* const* d_in, const int* in_sizes, int n_in,
                              void* d_out, int out_size, void* d_ws, size_t ws_size,
                              hipStream_t stream)
{
  (void)in_sizes; (void)n_in; (void)out_size;
  const float* ts   = (const float*)d_in[0];
  const int*   ei   = (const int*)d_in[1];
  const float* Wen0 = (const float*)d_in[2];
  const float* ben0 = (const float*)d_in[3];
  const float* Wen1 = (const float*)d_in[4];
  const float* ben1 = (const float*)d_in[5];
  const float* Wde0 = (const float*)d_in[6];
  const float* bde0 = (const float*)d_in[7];
  const float* Wde1 = (const float*)d_in[8];
  const float* bde1 = (const float*)d_in[9];
  const float* Wmu  = (const float*)d_in[10];
  const float* bmu  = (const float*)d_in[11];
  const float* Wlv  = (const float*)d_in[12];
  const float* blv  = (const float*)d_in[13];
  const float* Who  = (const float*)d_in[14];
  const float* bho  = (const float*)d_in[15];
  const float* Wholv= (const float*)d_in[16];
  const float* bholv= (const float*)d_in[17];
  const float* eps  = (const float*)d_in[18];
  u16*   ws   = (u16*)d_ws;
  float* dout = (float*)d_out;
  const bool save = ws_size >= WS_NEED_BYTES;

  adj_kernel<<<1, 256, 0, stream>>>(ei, ws);
  pack_kernel<<<336, 256, 0, stream>>>(Wen0, Wen1, Wde0, Wde1, Who, Wholv, ws);
  enc_main<<<64, 512, 0, stream>>>(ts, ben0, ben1, Wmu, bmu, Wlv, blv,
      bho, bholv, Wholv, eps, ws, ws + WS_ST, dout);
  if (save){
    dec_main<true><<<64, 512, 0, stream>>>(bde0, bde1, bho, bholv,
        ws, ws + WS_ST, ws + WS_H1, dout);
    outlv_kernel<<<dim3(32,63), 256, 0, stream>>>(ws + WS_H1, ws, bholv, dout);
  } else {
    dec_main<false><<<64, 512, 0, stream>>>(bde0, bde1, bho, bholv,
        ws, ws + WS_ST, ws, dout);
  }
}